// Round 6
// baseline (496.800 us; speedup 1.0000x reference)
//
#include <hip/hip_runtime.h>

#define N_NODES 100000
#define N_EDGES 1600000
#define HID 128
#define LAT 64
#define N_LAYERS 3
#define N_GRAPHS 1000
#define CAP 64                                    // slots per node (P(deg>=64)~1e-19)
#define NBIN 391                                  // dst bins of 256 nodes (d >> 8)
#define MAXBIN 4608                               // bin capacity: mean 4096 + 8*sigma
#define ACHUNK 8192
#define ABLOCKS ((N_EDGES + ACHUNK - 1) / ACHUNK) // 196
#define CVT_BLOCKS (N_NODES * HID / 4 / 256)      // 12500

typedef short bf16x8 __attribute__((ext_vector_type(8)));
typedef float f32x4 __attribute__((ext_vector_type(4)));

__device__ __forceinline__ float bf2f(unsigned short h) {
    union { unsigned int u; float f; } c;
    c.u = ((unsigned int)h) << 16;
    return c.f;
}
__device__ __forceinline__ unsigned short f2bf(float f) {
    union { float f; unsigned int u; } c;
    c.f = f;
    unsigned int u = c.u;
    return (unsigned short)((u + 0x7fffu + ((u >> 16) & 1u)) >> 16);
}
__device__ __forceinline__ unsigned int pack2(float a, float b) {
    return (unsigned int)f2bf(a) | ((unsigned int)f2bf(b) << 16);
}
__device__ __forceinline__ void addrow(float* acc, uint4 w) {
    acc[0] += bf2f((unsigned short)w.x); acc[1] += bf2f((unsigned short)(w.x >> 16));
    acc[2] += bf2f((unsigned short)w.y); acc[3] += bf2f((unsigned short)(w.y >> 16));
    acc[4] += bf2f((unsigned short)w.z); acc[5] += bf2f((unsigned short)(w.z >> 16));
    acc[6] += bf2f((unsigned short)w.w); acc[7] += bf2f((unsigned short)(w.w >> 16));
}

// ---------------- setup: binA (blocks [0,ABLOCKS)) + W transpose (next 6)
//                  + x fp32->bf16 convert (rest). Independent jobs, one launch.
__global__ __launch_bounds__(256) void setup_kernel(const int* __restrict__ ei,
                                                    int* __restrict__ gcnt,
                                                    unsigned int* __restrict__ ebin,
                                                    const float* __restrict__ x,
                                                    unsigned short* __restrict__ xb,
                                                    const float* __restrict__ W1,
                                                    const float* __restrict__ W2,
                                                    unsigned short* __restrict__ Wt) {
    __shared__ unsigned int scount[NBIN];
    __shared__ unsigned int sfill[NBIN];
    int t = threadIdx.x;
    int blk = blockIdx.x;
    if (blk >= ABLOCKS) {
        int b2 = blk - ABLOCKS;
        if (b2 < 6) {
            const float* W = ((b2 & 1) ? W2 : W1) + (size_t)(b2 >> 1) * HID * HID;
            unsigned short* D = Wt + (size_t)b2 * HID * HID;
            for (int idx = t; idx < HID * HID; idx += 256) {
                int n = idx >> 7, k = idx & 127;
                D[n * HID + k] = f2bf(W[k * HID + n]);
            }
            return;
        }
        int i = (b2 - 6) * 256 + t;
        if (i >= N_NODES * HID / 4) return;
        float4 v = ((const float4*)x)[i];
        ((uint2*)xb)[i] = make_uint2(pack2(v.x, v.y), pack2(v.z, v.w));
        return;
    }
    // ---- binA: edges -> per-bin dense runs, packed (dlocal<<24)|src ----
    int base = blk * ACHUNK;
    int n = N_EDGES - base;
    if (n > ACHUNK) n = ACHUNK;
    for (int i = t; i < NBIN; i += 256) scount[i] = 0u;
    __syncthreads();
    for (int i = t; i < n; i += 256) {
        int d = ei[N_EDGES + base + i];
        atomicAdd(&scount[d >> 8], 1u);
    }
    __syncthreads();
    for (int b = t; b < NBIN; b += 256) {
        unsigned int c = scount[b];
        sfill[b] = c ? (unsigned int)atomicAdd(&gcnt[b], (int)c) : 0u;
    }
    __syncthreads();
    for (int i = t; i < n; i += 256) {
        int s = ei[base + i];
        int d = ei[N_EDGES + base + i];
        int b = d >> 8;
        unsigned int pos = atomicAdd(&sfill[b], 1u);
        ebin[(size_t)b * MAXBIN + pos] = ((unsigned int)(d & 255) << 24) | (unsigned int)s;
    }
}

// ---------------- binB: drain bin -> slot csr, all block-local ----------------
__global__ __launch_bounds__(256) void binB_kernel(const unsigned int* __restrict__ ebin,
                                                   const int* __restrict__ gcnt,
                                                   int* __restrict__ cnt,
                                                   int* __restrict__ csr) {
    __shared__ int scnt[256];
    int b = blockIdx.x;
    int t = threadIdx.x;
    scnt[t] = 0;
    __syncthreads();
    int n0 = b << 8;
    int c = gcnt[b];
    const unsigned int* src = ebin + (size_t)b * MAXBIN;
    for (int i = t; i < c; i += 256) {
        unsigned int e = src[i];
        int dl = (int)(e >> 24);
        int slot = atomicAdd(&scnt[dl], 1);
        csr[(size_t)(n0 + dl) * CAP + slot] = (int)(e & 0xFFFFFFu);
    }
    __syncthreads();
    int node = n0 + t;
    if (node < N_NODES) cnt[node] = scnt[t];
}

// ---------------- gather (bf16): agg[n] = h[n] + sum_{s in N(n)} h[s] ----------
// Round-0 proven shape, but 512-thread blocks (32 nodes) to probe the
// workgroup-slot occupancy ceiling (round-0 @256thr: achieved occ 45% vs
// static 100%). Per-thread mapping identical; no LDS, no barriers.
__global__ __launch_bounds__(512) void gather_kernel(const unsigned short* __restrict__ h,
                                                     const int* __restrict__ cnt,
                                                     const int* __restrict__ csr,
                                                     unsigned short* __restrict__ agg) {
    int t = threadIdx.x;
    int node = blockIdx.x * 32 + (t >> 4);
    int q = t & 15;
    if (node >= N_NODES) return;
    const int* nl = csr + (size_t)node * CAP;
    int deg = cnt[node];
    float acc[8] = {0.f, 0.f, 0.f, 0.f, 0.f, 0.f, 0.f, 0.f};
    addrow(acc, *(const uint4*)(h + (size_t)node * HID + q * 8));
    int e = 0;
    for (; e + 8 <= deg; e += 8) {
        int s0 = nl[e], s1 = nl[e + 1], s2 = nl[e + 2], s3 = nl[e + 3];
        int s4 = nl[e + 4], s5 = nl[e + 5], s6 = nl[e + 6], s7 = nl[e + 7];
        uint4 w0 = *(const uint4*)(h + (size_t)s0 * HID + q * 8);
        uint4 w1 = *(const uint4*)(h + (size_t)s1 * HID + q * 8);
        uint4 w2 = *(const uint4*)(h + (size_t)s2 * HID + q * 8);
        uint4 w3 = *(const uint4*)(h + (size_t)s3 * HID + q * 8);
        uint4 w4 = *(const uint4*)(h + (size_t)s4 * HID + q * 8);
        uint4 w5 = *(const uint4*)(h + (size_t)s5 * HID + q * 8);
        uint4 w6 = *(const uint4*)(h + (size_t)s6 * HID + q * 8);
        uint4 w7 = *(const uint4*)(h + (size_t)s7 * HID + q * 8);
        addrow(acc, w0); addrow(acc, w1); addrow(acc, w2); addrow(acc, w3);
        addrow(acc, w4); addrow(acc, w5); addrow(acc, w6); addrow(acc, w7);
    }
    for (; e + 4 <= deg; e += 4) {
        int s0 = nl[e], s1 = nl[e + 1], s2 = nl[e + 2], s3 = nl[e + 3];
        uint4 w0 = *(const uint4*)(h + (size_t)s0 * HID + q * 8);
        uint4 w1 = *(const uint4*)(h + (size_t)s1 * HID + q * 8);
        uint4 w2 = *(const uint4*)(h + (size_t)s2 * HID + q * 8);
        uint4 w3 = *(const uint4*)(h + (size_t)s3 * HID + q * 8);
        addrow(acc, w0); addrow(acc, w1); addrow(acc, w2); addrow(acc, w3);
    }
    for (; e < deg; ++e) {
        addrow(acc, *(const uint4*)(h + (size_t)nl[e] * HID + q * 8));
    }
    uint4 o;
    o.x = pack2(acc[0], acc[1]);
    o.y = pack2(acc[2], acc[3]);
    o.z = pack2(acc[4], acc[5]);
    o.w = pack2(acc[6], acc[7]);
    *(uint4*)(agg + (size_t)node * HID + q * 8) = o;
}

// ---------------- lean MFMA MLP: 16 rows/block, W direct from L2 ----------
// Replaces the round-0 LDS-W-staged mlp (64 rows, 28KB LDS, 9 barriers,
// ~43us/layer vs ~10us memory floor). This is the R2-proven phase-2 shape
// run STANDALONE: grid 6250, 4 waves x 2 N-tiles, W-fragments loaded from
// L2 inside the kc loop (VGPR ~48 -> 8 waves/SIMD), LDS 4.4KB, 3 barriers.
// Standalone, all 32 waves/CU stream W-loads continuously -> L2 latency
// pipelines across waves (unlike the convoy-locked fused variant).
__global__ __launch_bounds__(256) void mlp2_kernel(const unsigned short* __restrict__ A,
                                                   const unsigned short* __restrict__ W1t,
                                                   const float* __restrict__ b1,
                                                   const unsigned short* __restrict__ W2t,
                                                   const float* __restrict__ b2,
                                                   unsigned short* __restrict__ out,
                                                   const int* __restrict__ batch,
                                                   float* __restrict__ gpool) {
    __shared__ unsigned short sA[16][136];  // row stride 272B = 17*16B
    __shared__ int sbatch[16];
    const int t = threadIdx.x;
    const int w = t >> 6;
    const int l = t & 63;
    const int lm = l & 15;
    const int quad = l >> 4;
    const int row0 = blockIdx.x * 16;

    // A tile: 256 uint4, one per thread
    {
        int r = t >> 4, c = t & 15;
        int grow = row0 + r;
        uint4 v = make_uint4(0u, 0u, 0u, 0u);
        if (grow < N_NODES) v = *(const uint4*)(A + (size_t)grow * HID + c * 8);
        *(uint4*)&sA[r][c * 8] = v;
    }
    if (gpool && t < 16) {
        int n = row0 + t;
        sbatch[t] = (n < N_NODES) ? batch[n] : -1;
    }
    __syncthreads();

    const int n0a = (2 * w) * 16 + lm;
    const int n0b = (2 * w + 1) * 16 + lm;
    const unsigned short* Wt2[2] = {W1t, W2t};
    const float* bias[2] = {b1, b2};

    for (int p = 0; p < 2; ++p) {
        f32x4 acc0 = (f32x4){0.f, 0.f, 0.f, 0.f};
        f32x4 acc1 = (f32x4){0.f, 0.f, 0.f, 0.f};
        const unsigned short* Wp = Wt2[p];
#pragma unroll
        for (int kc = 0; kc < 4; ++kc) {
            bf16x8 a = *(const bf16x8*)&sA[lm][kc * 32 + quad * 8];
            bf16x8 bfr0 = *(const bf16x8*)(Wp + (size_t)n0a * HID + kc * 32 + quad * 8);
            bf16x8 bfr1 = *(const bf16x8*)(Wp + (size_t)n0b * HID + kc * 32 + quad * 8);
            acc0 = __builtin_amdgcn_mfma_f32_16x16x32_bf16(a, bfr0, acc0, 0, 0, 0);
            acc1 = __builtin_amdgcn_mfma_f32_16x16x32_bf16(a, bfr1, acc1, 0, 0, 0);
        }
        __syncthreads();   // all sA reads done before overwrite
        float bv0 = bias[p][n0a];
        float bv1 = bias[p][n0b];
#pragma unroll
        for (int r = 0; r < 4; ++r) {
            int m = quad * 4 + r;
            sA[m][n0a] = f2bf(fmaxf(acc0[r] + bv0, 0.f));
            sA[m][n0b] = f2bf(fmaxf(acc1[r] + bv1, 0.f));
        }
        __syncthreads();
    }

    if (!gpool) {
        int r = t >> 4, c = t & 15;
        int grow = row0 + r;
        if (grow < N_NODES)
            *(uint4*)(out + (size_t)grow * HID + c * 8) = *(const uint4*)&sA[r][c * 8];
    } else {
        // fused global_add_pool: thread t covers channel (t&127), rows [(t>>7)*8, +8)
        int c = t & 127;
        int r0 = (t >> 7) * 8;
        float acc = 0.f;
        int cur = sbatch[r0];
        for (int r = r0; r < r0 + 8; ++r) {
            int b = sbatch[r];
            if (b < 0) break;
            if (b != cur) {
                atomicAdd(&gpool[(size_t)cur * HID + c], acc);
                acc = 0.f;
                cur = b;
            }
            acc += bf2f(sA[r][c]);
        }
        if (cur >= 0) atomicAdd(&gpool[(size_t)cur * HID + c], acc);
    }
}

// ---------------- heads ----------------
__global__ __launch_bounds__(128) void head_kernel(const float* __restrict__ g,
                                                   const float* __restrict__ Wmu,
                                                   const float* __restrict__ bmu,
                                                   const float* __restrict__ Wlv,
                                                   const float* __restrict__ blv,
                                                   float* __restrict__ out) {
    __shared__ float sg[HID];
    int gi = blockIdx.x;
    sg[threadIdx.x] = g[(size_t)gi * HID + threadIdx.x];
    __syncthreads();
    int j = threadIdx.x & 63;
    bool is_lv = threadIdx.x >= 64;
    const float* W = is_lv ? Wlv : Wmu;
    float acc = is_lv ? blv[j] : bmu[j];
    for (int k = 0; k < HID; ++k) acc = fmaf(sg[k], W[k * LAT + j], acc);
    out[(is_lv ? (size_t)N_GRAPHS * LAT : 0) + (size_t)gi * LAT + j] = acc;
}

extern "C" void kernel_launch(void* const* d_in, const int* in_sizes, int n_in,
                              void* d_out, int out_size, void* d_ws, size_t ws_size,
                              hipStream_t stream) {
    const float* x     = (const float*)d_in[0];
    const int*   ei    = (const int*)d_in[1];
    const int*   batch = (const int*)d_in[2];
    const float* W1    = (const float*)d_in[3];
    const float* b1    = (const float*)d_in[4];
    const float* W2    = (const float*)d_in[5];
    const float* b2    = (const float*)d_in[6];
    const float* Wmu   = (const float*)d_in[7];
    const float* bmu   = (const float*)d_in[8];
    const float* Wlv   = (const float*)d_in[9];
    const float* blv   = (const float*)d_in[10];
    float* out = (float*)d_out;

    // 256B-aligned layout: all row-addressed buffers first (every size is a
    // multiple of 256B), small int arrays last. (R13 lesson: a 1568B offset
    // made every 256B row span 5 lines instead of 4 -> +43% gather FETCH.)
    unsigned short* xb   = (unsigned short*)d_ws;                  // 25.6 MB
    unsigned short* agg  = xb + (size_t)N_NODES * HID;             // 25.6 MB
    unsigned short* hbuf = agg + (size_t)N_NODES * HID;            // 25.6 MB
    int* csr = (int*)(hbuf + (size_t)N_NODES * HID);               // 25.6 MB
    unsigned int* ebin = (unsigned int*)(csr + (size_t)N_NODES * CAP);  // 7,206,912 B
    unsigned short* Wt = (unsigned short*)(ebin + (size_t)NBIN * MAXBIN); // 196,608 B
    float* g  = (float*)(Wt + (size_t)6 * HID * HID);              // 512,000 B
    int* gcnt = (int*)(g + (size_t)N_GRAPHS * HID);                // adjacent to g
    int* cnt  = gcnt + NBIN + 1;

    hipMemsetAsync(g, 0, (size_t)N_GRAPHS * HID * sizeof(float) + (NBIN + 1) * sizeof(int),
                   stream);

    // ---- setup: binA + W transpose + x->bf16, one launch ----
    setup_kernel<<<ABLOCKS + 6 + CVT_BLOCKS, 256, 0, stream>>>(ei, gcnt, ebin,
                                                               x, xb, W1, W2, Wt);
    // ---- CSR finalize ----
    binB_kernel<<<NBIN, 256, 0, stream>>>(ebin, gcnt, cnt, csr);

    const unsigned short* hcur = xb;
    for (int i = 0; i < N_LAYERS; ++i) {
        bool last = (i == N_LAYERS - 1);
        gather_kernel<<<(N_NODES + 31) / 32, 512, 0, stream>>>(hcur, cnt, csr, agg);
        mlp2_kernel<<<(N_NODES + 15) / 16, 256, 0, stream>>>(
            agg, Wt + (size_t)(2 * i) * HID * HID, b1 + (size_t)i * HID,
            Wt + (size_t)(2 * i + 1) * HID * HID, b2 + (size_t)i * HID, hbuf,
            batch, last ? g : nullptr);
        hcur = hbuf;
    }
    head_kernel<<<N_GRAPHS, 128, 0, stream>>>(g, Wmu, bmu, Wlv, blv, out);
}

// Round 7
// 408.555 us; speedup vs baseline: 1.2160x; 1.2160x over previous
//
#include <hip/hip_runtime.h>

#define N_NODES 100000
#define N_EDGES 1600000
#define HID 128
#define LAT 64
#define N_LAYERS 3
#define N_GRAPHS 1000
#define CAP 64                                    // slots per node (P(deg>=64)~1e-19)
#define NBIN 391                                  // dst bins of 256 nodes (d >> 8)
#define MAXBIN 4608                               // bin capacity: mean 4096 + 8*sigma
#define ACHUNK 8192
#define ABLOCKS ((N_EDGES + ACHUNK - 1) / ACHUNK) // 196
#define CVT_BLOCKS (N_NODES * HID / 4 / 256)      // 12500

typedef short bf16x8 __attribute__((ext_vector_type(8)));
typedef float f32x4 __attribute__((ext_vector_type(4)));

__device__ __forceinline__ float bf2f(unsigned short h) {
    union { unsigned int u; float f; } c;
    c.u = ((unsigned int)h) << 16;
    return c.f;
}
__device__ __forceinline__ unsigned short f2bf(float f) {
    union { float f; unsigned int u; } c;
    c.f = f;
    unsigned int u = c.u;
    return (unsigned short)((u + 0x7fffu + ((u >> 16) & 1u)) >> 16);
}
__device__ __forceinline__ unsigned int pack2(float a, float b) {
    return (unsigned int)f2bf(a) | ((unsigned int)f2bf(b) << 16);
}
__device__ __forceinline__ void addrow(float* acc, uint4 w) {
    acc[0] += bf2f((unsigned short)w.x); acc[1] += bf2f((unsigned short)(w.x >> 16));
    acc[2] += bf2f((unsigned short)w.y); acc[3] += bf2f((unsigned short)(w.y >> 16));
    acc[4] += bf2f((unsigned short)w.z); acc[5] += bf2f((unsigned short)(w.z >> 16));
    acc[6] += bf2f((unsigned short)w.w); acc[7] += bf2f((unsigned short)(w.w >> 16));
}

// ---------------- setup: binA (blocks [0,ABLOCKS)) + W transpose (next 6)
//                  + x fp32->bf16 convert (rest). Independent jobs, one launch
//                  (in-stream they'd serialize as separate kernels).
__global__ __launch_bounds__(256) void setup_kernel(const int* __restrict__ ei,
                                                    int* __restrict__ gcnt,
                                                    unsigned int* __restrict__ ebin,
                                                    const float* __restrict__ x,
                                                    unsigned short* __restrict__ xb,
                                                    const float* __restrict__ W1,
                                                    const float* __restrict__ W2,
                                                    unsigned short* __restrict__ Wt) {
    __shared__ unsigned int scount[NBIN];
    __shared__ unsigned int sfill[NBIN];
    int t = threadIdx.x;
    int blk = blockIdx.x;
    if (blk >= ABLOCKS) {
        int b2 = blk - ABLOCKS;
        if (b2 < 6) {
            const float* W = ((b2 & 1) ? W2 : W1) + (size_t)(b2 >> 1) * HID * HID;
            unsigned short* D = Wt + (size_t)b2 * HID * HID;
            for (int idx = t; idx < HID * HID; idx += 256) {
                int n = idx >> 7, k = idx & 127;
                D[n * HID + k] = f2bf(W[k * HID + n]);
            }
            return;
        }
        int i = (b2 - 6) * 256 + t;
        if (i >= N_NODES * HID / 4) return;
        float4 v = ((const float4*)x)[i];
        ((uint2*)xb)[i] = make_uint2(pack2(v.x, v.y), pack2(v.z, v.w));
        return;
    }
    // ---- binA: edges -> per-bin dense runs, packed (dlocal<<24)|src ----
    int base = blk * ACHUNK;
    int n = N_EDGES - base;
    if (n > ACHUNK) n = ACHUNK;
    for (int i = t; i < NBIN; i += 256) scount[i] = 0u;
    __syncthreads();
    for (int i = t; i < n; i += 256) {
        int d = ei[N_EDGES + base + i];
        atomicAdd(&scount[d >> 8], 1u);
    }
    __syncthreads();
    for (int b = t; b < NBIN; b += 256) {
        unsigned int c = scount[b];
        sfill[b] = c ? (unsigned int)atomicAdd(&gcnt[b], (int)c) : 0u;
    }
    __syncthreads();
    for (int i = t; i < n; i += 256) {
        int s = ei[base + i];
        int d = ei[N_EDGES + base + i];
        int b = d >> 8;
        unsigned int pos = atomicAdd(&sfill[b], 1u);
        ebin[(size_t)b * MAXBIN + pos] = ((unsigned int)(d & 255) << 24) | (unsigned int)s;
    }
}

// ---------------- binB: drain bin -> slot csr via LDS, coalesced writeout ----
// R0 binB scattered ~1.6M time-separated 4B stores into csr (~100MB of
// effective transactions). Now: each block owns a HALF-bin (128 nodes),
// builds the 128x64 slot table in 32KB LDS, then writes csr as contiguous
// int4 (25.6MB coalesced total). ebin read twice (12.8MB) -- cheap.
__global__ __launch_bounds__(256) void binB_kernel(const unsigned int* __restrict__ ebin,
                                                   const int* __restrict__ gcnt,
                                                   int* __restrict__ cnt,
                                                   int* __restrict__ csr) {
    __shared__ int lcsr[128][CAP];   // 32KB
    __shared__ int scnt[128];
    int blk = blockIdx.x;
    int b = blk >> 1;
    int half = blk & 1;
    int t = threadIdx.x;
    if (t < 128) scnt[t] = 0;
    __syncthreads();
    int c = gcnt[b];
    const unsigned int* src = ebin + (size_t)b * MAXBIN;
    for (int i = t; i < c; i += 256) {
        unsigned int e = src[i];
        int dl = (int)(e >> 24);
        if ((dl >> 7) == half) {
            int slot = atomicAdd(&scnt[dl & 127], 1);
            lcsr[dl & 127][slot] = (int)(e & 0xFFFFFFu);
        }
    }
    __syncthreads();
    int n0 = (b << 8) + (half << 7);
    if (t < 128 && n0 + t < N_NODES) cnt[n0 + t] = scnt[t];
    int nv = N_NODES - n0;
    if (nv > 128) nv = 128;
    if (nv < 0) nv = 0;
    int4* dst = (int4*)(csr + (size_t)n0 * CAP);
    const int4* ls = (const int4*)&lcsr[0][0];
    for (int i = t; i < nv * (CAP / 4); i += 256) dst[i] = ls[i];
}

// ---------------- gather (bf16): round-0 EXACT (61.5us proven shape) --------
__global__ __launch_bounds__(256) void gather_kernel(const unsigned short* __restrict__ h,
                                                     const int* __restrict__ cnt,
                                                     const int* __restrict__ csr,
                                                     unsigned short* __restrict__ agg) {
    int t = threadIdx.x;
    int node = blockIdx.x * 16 + (t >> 4);
    int q = t & 15;
    if (node >= N_NODES) return;
    const int* nl = csr + (size_t)node * CAP;
    int deg = cnt[node];
    float acc[8] = {0.f, 0.f, 0.f, 0.f, 0.f, 0.f, 0.f, 0.f};
    addrow(acc, *(const uint4*)(h + (size_t)node * HID + q * 8));
    int e = 0;
    for (; e + 8 <= deg; e += 8) {
        int s0 = nl[e], s1 = nl[e + 1], s2 = nl[e + 2], s3 = nl[e + 3];
        int s4 = nl[e + 4], s5 = nl[e + 5], s6 = nl[e + 6], s7 = nl[e + 7];
        uint4 w0 = *(const uint4*)(h + (size_t)s0 * HID + q * 8);
        uint4 w1 = *(const uint4*)(h + (size_t)s1 * HID + q * 8);
        uint4 w2 = *(const uint4*)(h + (size_t)s2 * HID + q * 8);
        uint4 w3 = *(const uint4*)(h + (size_t)s3 * HID + q * 8);
        uint4 w4 = *(const uint4*)(h + (size_t)s4 * HID + q * 8);
        uint4 w5 = *(const uint4*)(h + (size_t)s5 * HID + q * 8);
        uint4 w6 = *(const uint4*)(h + (size_t)s6 * HID + q * 8);
        uint4 w7 = *(const uint4*)(h + (size_t)s7 * HID + q * 8);
        addrow(acc, w0); addrow(acc, w1); addrow(acc, w2); addrow(acc, w3);
        addrow(acc, w4); addrow(acc, w5); addrow(acc, w6); addrow(acc, w7);
    }
    for (; e + 4 <= deg; e += 4) {
        int s0 = nl[e], s1 = nl[e + 1], s2 = nl[e + 2], s3 = nl[e + 3];
        uint4 w0 = *(const uint4*)(h + (size_t)s0 * HID + q * 8);
        uint4 w1 = *(const uint4*)(h + (size_t)s1 * HID + q * 8);
        uint4 w2 = *(const uint4*)(h + (size_t)s2 * HID + q * 8);
        uint4 w3 = *(const uint4*)(h + (size_t)s3 * HID + q * 8);
        addrow(acc, w0); addrow(acc, w1); addrow(acc, w2); addrow(acc, w3);
    }
    for (; e < deg; ++e) {
        addrow(acc, *(const uint4*)(h + (size_t)nl[e] * HID + q * 8));
    }
    uint4 o;
    o.x = pack2(acc[0], acc[1]);
    o.y = pack2(acc[2], acc[3]);
    o.z = pack2(acc[4], acc[5]);
    o.w = pack2(acc[6], acc[7]);
    *(uint4*)(agg + (size_t)node * HID + q * 8) = o;
}

// ---------------- MFMA MLP (round-0 core) + T14 async-staged sW -------------
// R0 stalled between each kc's barrier pair on ~400cyc L2 W-loads (8x/block).
// Now the stage is split: global loads for step s+1 are ISSUED right after
// step s's ds_write (latency hides under the 8 MFMAs + barrier); between
// barriers only the fast ds_write remains. LDS unchanged 28.7KB; +8 VGPR
// (stays inside the 64..128 occupancy band).
__global__ __launch_bounds__(256) void mlp_kernel(const unsigned short* __restrict__ A,
                                                  const unsigned short* __restrict__ W1t,
                                                  const float* __restrict__ b1,
                                                  const unsigned short* __restrict__ W2t,
                                                  const float* __restrict__ b2,
                                                  unsigned short* __restrict__ out,
                                                  const int* __restrict__ batch,
                                                  float* __restrict__ gpool) {
    __shared__ unsigned short sA[64][136];  // row stride 272B = 17*16B
    __shared__ unsigned short sW[128][40];  // row stride 80B = 5*16B
    __shared__ float sb[128];
    __shared__ int sbatch[64];
    const int t = threadIdx.x;
    const int w = t >> 6;
    const int l = t & 63;
    const int lm = l & 15;
    const int quad = l >> 4;
    const int row0 = blockIdx.x * 64;

    for (int idx = t; idx < 1024; idx += 256) {
        int r = idx >> 4, c = idx & 15;
        int grow = row0 + r;
        uint4 v = make_uint4(0u, 0u, 0u, 0u);
        if (grow < N_NODES) v = *(const uint4*)(A + (size_t)grow * HID + c * 8);
        *(uint4*)&sA[r][c * 8] = v;
    }
    if (gpool && t < 64) {
        int n = row0 + t;
        sbatch[t] = (n < N_NODES) ? batch[n] : -1;
    }

    const unsigned short* Wt2[2] = {W1t, W2t};
    const float* bias[2] = {b1, b2};

    // stage-register prologue: this thread covers sW elements t and t+256
    const int n_0 = t >> 2;
    const int n_1 = (t >> 2) + 64;
    const int kq = t & 3;
    uint4 rw0 = *(const uint4*)(W1t + (size_t)n_0 * HID + kq * 8);
    uint4 rw1 = *(const uint4*)(W1t + (size_t)n_1 * HID + kq * 8);

    for (int p = 0; p < 2; ++p) {
        if (t < 128) sb[t] = bias[p][t];
        f32x4 acc[8];
#pragma unroll
        for (int nt = 0; nt < 8; ++nt) acc[nt] = (f32x4){0.f, 0.f, 0.f, 0.f};

        for (int kc = 0; kc < 4; ++kc) {
            __syncthreads();   // prior consumers of sW done (also covers A-tile)
            *(uint4*)&sW[n_0][kq * 8] = rw0;
            *(uint4*)&sW[n_1][kq * 8] = rw1;
            __syncthreads();
            int s = (p << 2) + kc;
            if (s < 7) {       // issue next stage's loads; land during MFMAs
                int pn = (s + 1) >> 2, kn = (s + 1) & 3;
                const unsigned short* Wn = Wt2[pn];
                rw0 = *(const uint4*)(Wn + (size_t)n_0 * HID + kn * 32 + kq * 8);
                rw1 = *(const uint4*)(Wn + (size_t)n_1 * HID + kn * 32 + kq * 8);
            }
            bf16x8 a = *(const bf16x8*)&sA[w * 16 + lm][kc * 32 + quad * 8];
#pragma unroll
            for (int nt = 0; nt < 8; ++nt) {
                bf16x8 b = *(const bf16x8*)&sW[nt * 16 + lm][quad * 8];
                acc[nt] = __builtin_amdgcn_mfma_f32_16x16x32_bf16(a, b, acc[nt], 0, 0, 0);
            }
        }
        __syncthreads();
#pragma unroll
        for (int nt = 0; nt < 8; ++nt) {
            float bv = sb[nt * 16 + lm];
#pragma unroll
            for (int r = 0; r < 4; ++r) {
                int m = w * 16 + quad * 4 + r;
                float val = fmaxf(acc[nt][r] + bv, 0.f);
                sA[m][nt * 16 + lm] = f2bf(val);
            }
        }
        __syncthreads();
    }

    if (!gpool) {
        for (int idx = t; idx < 1024; idx += 256) {
            int r = idx >> 4, c = idx & 15;
            int grow = row0 + r;
            if (grow < N_NODES)
                *(uint4*)(out + (size_t)grow * HID + c * 8) = *(const uint4*)&sA[r][c * 8];
        }
    } else {
        // fused global_add_pool: thread t covers channel (t&127), rows [(t>>7)*32, +32)
        int c = t & 127;
        int r0 = (t >> 7) * 32;
        float acc = 0.f;
        int cur = sbatch[r0];
        for (int r = r0; r < r0 + 32; ++r) {
            int b = sbatch[r];
            if (b < 0) break;
            if (b != cur) {
                atomicAdd(&gpool[(size_t)cur * HID + c], acc);
                acc = 0.f;
                cur = b;
            }
            acc += bf2f(sA[r][c]);
        }
        if (cur >= 0) atomicAdd(&gpool[(size_t)cur * HID + c], acc);
    }
}

// ---------------- heads ----------------
__global__ __launch_bounds__(128) void head_kernel(const float* __restrict__ g,
                                                   const float* __restrict__ Wmu,
                                                   const float* __restrict__ bmu,
                                                   const float* __restrict__ Wlv,
                                                   const float* __restrict__ blv,
                                                   float* __restrict__ out) {
    __shared__ float sg[HID];
    int gi = blockIdx.x;
    sg[threadIdx.x] = g[(size_t)gi * HID + threadIdx.x];
    __syncthreads();
    int j = threadIdx.x & 63;
    bool is_lv = threadIdx.x >= 64;
    const float* W = is_lv ? Wlv : Wmu;
    float acc = is_lv ? blv[j] : bmu[j];
    for (int k = 0; k < HID; ++k) acc = fmaf(sg[k], W[k * LAT + j], acc);
    out[(is_lv ? (size_t)N_GRAPHS * LAT : 0) + (size_t)gi * LAT + j] = acc;
}

extern "C" void kernel_launch(void* const* d_in, const int* in_sizes, int n_in,
                              void* d_out, int out_size, void* d_ws, size_t ws_size,
                              hipStream_t stream) {
    const float* x     = (const float*)d_in[0];
    const int*   ei    = (const int*)d_in[1];
    const int*   batch = (const int*)d_in[2];
    const float* W1    = (const float*)d_in[3];
    const float* b1    = (const float*)d_in[4];
    const float* W2    = (const float*)d_in[5];
    const float* b2    = (const float*)d_in[6];
    const float* Wmu   = (const float*)d_in[7];
    const float* bmu   = (const float*)d_in[8];
    const float* Wlv   = (const float*)d_in[9];
    const float* blv   = (const float*)d_in[10];
    float* out = (float*)d_out;

    // 256B-aligned layout: all row-addressed buffers first (every size is a
    // multiple of 256B), small int arrays last. (R13 lesson: a 1568B offset
    // made every 256B row span 5 lines instead of 4 -> +43% gather FETCH.)
    unsigned short* xb   = (unsigned short*)d_ws;                  // 25.6 MB
    unsigned short* agg  = xb + (size_t)N_NODES * HID;             // 25.6 MB
    unsigned short* hbuf = agg + (size_t)N_NODES * HID;            // 25.6 MB
    int* csr = (int*)(hbuf + (size_t)N_NODES * HID);               // 25.6 MB
    unsigned int* ebin = (unsigned int*)(csr + (size_t)N_NODES * CAP);  // 7,206,912 B
    unsigned short* Wt = (unsigned short*)(ebin + (size_t)NBIN * MAXBIN); // 196,608 B
    float* g  = (float*)(Wt + (size_t)6 * HID * HID);              // 512,000 B
    int* gcnt = (int*)(g + (size_t)N_GRAPHS * HID);                // adjacent to g
    int* cnt  = gcnt + NBIN + 1;

    hipMemsetAsync(g, 0, (size_t)N_GRAPHS * HID * sizeof(float) + (NBIN + 1) * sizeof(int),
                   stream);

    // ---- setup: binA + W transpose + x->bf16, one launch ----
    setup_kernel<<<ABLOCKS + 6 + CVT_BLOCKS, 256, 0, stream>>>(ei, gcnt, ebin,
                                                               x, xb, W1, W2, Wt);
    // ---- CSR finalize: LDS-staged, coalesced writeout ----
    binB_kernel<<<NBIN * 2, 256, 0, stream>>>(ebin, gcnt, cnt, csr);

    const unsigned short* hcur = xb;
    for (int i = 0; i < N_LAYERS; ++i) {
        bool last = (i == N_LAYERS - 1);
        gather_kernel<<<(N_NODES + 15) / 16, 256, 0, stream>>>(hcur, cnt, csr, agg);
        mlp_kernel<<<(N_NODES + 63) / 64, 256, 0, stream>>>(
            agg, Wt + (size_t)(2 * i) * HID * HID, b1 + (size_t)i * HID,
            Wt + (size_t)(2 * i + 1) * HID * HID, b2 + (size_t)i * HID, hbuf,
            batch, last ? g : nullptr);
        hcur = hbuf;
    }
    head_kernel<<<N_GRAPHS, 128, 0, stream>>>(g, Wmu, bmu, Wlv, blv, out);
}